// Round 1
// baseline (1082.350 us; speedup 1.0000x reference)
//
#include <hip/hip_runtime.h>
#include <hip/hip_bf16.h>

typedef __attribute__((ext_vector_type(8))) short short8;
typedef __attribute__((ext_vector_type(4))) float f32x4;
typedef unsigned int uint;

#define T_TOK 8192
#define D_DIM 1024
#define F_DIM 4096
#define E_NUM 8
#define KTOP 2

// ---------------------------------------------------------------------------
// fp32 -> bf16 convert (8 elems/thread/iter, vectorized)
// ---------------------------------------------------------------------------
__global__ void cvt_kernel(const float* __restrict__ in, short* __restrict__ out, int n8) {
    int i = blockIdx.x * blockDim.x + threadIdx.x;
    int stride = gridDim.x * blockDim.x;
    for (; i < n8; i += stride) {
        const float4* p = (const float4*)(in + (size_t)i * 8);
        float4 a = p[0], b = p[1];
        float va[8] = {a.x, a.y, a.z, a.w, b.x, b.y, b.z, b.w};
        short8 o;
#pragma unroll
        for (int j = 0; j < 8; ++j) {
            __hip_bfloat16 h = __float2bfloat16(va[j]);
            o[j] = *reinterpret_cast<short*>(&h);
        }
        *(short8*)(out + (size_t)i * 8) = o;
    }
}

// ---------------------------------------------------------------------------
// Gate: logits (fp32), softmax -> probs output, top-2, counts
// One wave per token; 4 tokens per 256-thread block.
// ---------------------------------------------------------------------------
__global__ void gate_kernel(const float* __restrict__ x, const float* __restrict__ gw,
                            float* __restrict__ probs, int4* __restrict__ idxrank,
                            float2* __restrict__ ww, int* __restrict__ counts) {
    const int lane = threadIdx.x & 63;
    const int wid = threadIdx.x >> 6;
    const int t = blockIdx.x * 4 + wid;
    const float4* xr = (const float4*)(x + (size_t)t * D_DIM);
    float acc[E_NUM];
#pragma unroll
    for (int e = 0; e < E_NUM; ++e) acc[e] = 0.f;
    for (int i = lane; i < D_DIM / 4; i += 64) {
        float4 xv = xr[i];
#pragma unroll
        for (int e = 0; e < E_NUM; ++e) {
            float4 gv = ((const float4*)(gw + (size_t)e * D_DIM))[i];
            acc[e] += xv.x * gv.x + xv.y * gv.y + xv.z * gv.z + xv.w * gv.w;
        }
    }
#pragma unroll
    for (int e = 0; e < E_NUM; ++e) {
#pragma unroll
        for (int off = 32; off > 0; off >>= 1) acc[e] += __shfl_xor(acc[e], off);
    }
    if (lane == 0) {
        float m = acc[0];
        for (int e = 1; e < E_NUM; ++e) m = fmaxf(m, acc[e]);
        float p[E_NUM], s = 0.f;
        for (int e = 0; e < E_NUM; ++e) { p[e] = expf(acc[e] - m); s += p[e]; }
        float inv = 1.f / s;
        for (int e = 0; e < E_NUM; ++e) {
            p[e] *= inv;
            probs[(size_t)t * E_NUM + e] = p[e];
        }
        float v0 = -1.f, v1 = -1.f; int i0 = 0, i1 = 0;
        for (int e = 0; e < E_NUM; ++e) {
            float v = p[e];
            if (v > v0) { v1 = v0; i1 = i0; v0 = v; i0 = e; }
            else if (v > v1) { v1 = v; i1 = e; }
        }
        float wsum = v0 + v1 + 1e-9f;
        int r0 = atomicAdd(&counts[i0], 1);
        int r1 = atomicAdd(&counts[i1], 1);
        idxrank[t] = make_int4(i0, i1, r0, r1);
        ww[t] = make_float2(v0 / wsum, v1 / wsum);
    }
}

// ---------------------------------------------------------------------------
// Exclusive prefix sum over 8 expert counts (trivial)
// ---------------------------------------------------------------------------
__global__ void scan_kernel(const int* __restrict__ counts, int* __restrict__ offs) {
    if (threadIdx.x == 0 && blockIdx.x == 0) {
        int a = 0;
        for (int e = 0; e < E_NUM; ++e) { offs[e] = a; a += counts[e]; }
        offs[E_NUM] = a;
    }
}

// ---------------------------------------------------------------------------
// Scatter tokens into expert-grouped slot lists
// ---------------------------------------------------------------------------
__global__ void scatter_kernel(const int4* __restrict__ idxrank, const float2* __restrict__ ww,
                               const int* __restrict__ offs, int* __restrict__ token_list,
                               float* __restrict__ slot_w) {
    int t = blockIdx.x * blockDim.x + threadIdx.x;
    if (t >= T_TOK) return;
    int4 ir = idxrank[t];
    float2 w = ww[t];
    int s0 = offs[ir.x] + ir.z;
    int s1 = offs[ir.y] + ir.w;
    token_list[s0] = t; slot_w[s0] = w.x;
    token_list[s1] = t; slot_w[s1] = w.y;
}

// ---------------------------------------------------------------------------
// global -> LDS direct (16B per lane)
// ---------------------------------------------------------------------------
__device__ __forceinline__ void gload16(const void* g, void* l) {
    __builtin_amdgcn_global_load_lds((const __attribute__((address_space(1))) uint*)g,
                                     (__attribute__((address_space(3))) uint*)l, 16, 0, 0);
}

// ---------------------------------------------------------------------------
// Grouped GEMM1: H[slot, :] = gelu( x[token_list[slot], :] @ w1[e]^T + b1[e] )
// 128x128 tile, BK=32, 4 waves (2x2), 16x16x32 bf16 MFMA (m97 structure).
// Both A and B stored [row, K] (B^T layout).
// ---------------------------------------------------------------------------
__global__ void gemm1_kernel(const short* __restrict__ xb, const short* __restrict__ w1b,
                             const float* __restrict__ b1, const int* __restrict__ offs,
                             const int* __restrict__ token_list, short* __restrict__ H) {
    const int e = blockIdx.z, mt = blockIdx.y, nt = blockIdx.x;
    const int base = offs[e];
    const int cnt = offs[e + 1] - base;
    if (mt * 128 >= cnt) return;

    __shared__ __align__(16) short sA[128 * 32];
    __shared__ __align__(16) short sB[128 * 32];

    const int tid = threadIdx.x, wid = tid >> 6, lane = tid & 63;

    const short* srcA[2];
    const short* srcB[2];
#pragma unroll
    for (int j = 0; j < 2; ++j) {
        int c = j * 256 + tid;
        int row = c >> 2, c8 = c & 3;
        int slot = base + mt * 128 + row;
        int slotc = min(slot, base + cnt - 1);
        int tok = token_list[slotc];
        srcA[j] = xb + (size_t)tok * D_DIM + c8 * 8;
        srcB[j] = w1b + ((size_t)e * F_DIM + nt * 128 + row) * D_DIM + c8 * 8;
    }

    const int wm = wid >> 1, wn = wid & 1;
    const int fr = lane & 15, fk = lane >> 4;

    f32x4 acc[4][4];
#pragma unroll
    for (int i = 0; i < 4; ++i)
#pragma unroll
        for (int j = 0; j < 4; ++j) acc[i][j] = (f32x4){0.f, 0.f, 0.f, 0.f};

    for (int k0 = 0; k0 < D_DIM; k0 += 32) {
#pragma unroll
        for (int j = 0; j < 2; ++j) {
            gload16(srcA[j] + k0, &sA[(j * 256 + wid * 64) * 8]);
            gload16(srcB[j] + k0, &sB[(j * 256 + wid * 64) * 8]);
        }
        __syncthreads();
        short8 af[4], bfr[4];
#pragma unroll
        for (int i = 0; i < 4; ++i) af[i] = *(const short8*)&sA[(wm * 64 + i * 16 + fr) * 32 + fk * 8];
#pragma unroll
        for (int i = 0; i < 4; ++i) bfr[i] = *(const short8*)&sB[(wn * 64 + i * 16 + fr) * 32 + fk * 8];
#pragma unroll
        for (int i = 0; i < 4; ++i)
#pragma unroll
            for (int j = 0; j < 4; ++j)
                acc[i][j] = __builtin_amdgcn_mfma_f32_16x16x32_bf16(af[i], bfr[j], acc[i][j], 0, 0, 0);
        __syncthreads();
    }

    // epilogue: bias + exact GELU -> bf16 H
#pragma unroll
    for (int i = 0; i < 4; ++i) {
        int mrow_base = mt * 128 + wm * 64 + i * 16 + (lane >> 4) * 4;
#pragma unroll
        for (int j = 0; j < 4; ++j) {
            int ncol = nt * 128 + wn * 64 + j * 16 + (lane & 15);
            float bias = b1[(size_t)e * F_DIM + ncol];
#pragma unroll
            for (int r = 0; r < 4; ++r) {
                int mrow = mrow_base + r;
                if (mrow < cnt) {
                    float v = acc[i][j][r] + bias;
                    v = 0.5f * v * (1.f + erff(v * 0.70710678118654752f));
                    __hip_bfloat16 h = __float2bfloat16(v);
                    H[(size_t)(base + mrow) * F_DIM + ncol] = *reinterpret_cast<short*>(&h);
                }
            }
        }
    }
}

// ---------------------------------------------------------------------------
// Grouped GEMM2: out[token, :] += slot_w * ( H[slot, :] @ w2[e]^T + b2[e] )
// Same structure, K=4096, fp32 atomicAdd epilogue.
// ---------------------------------------------------------------------------
__global__ void gemm2_kernel(const short* __restrict__ H, const short* __restrict__ w2b,
                             const float* __restrict__ b2, const int* __restrict__ offs,
                             const int* __restrict__ token_list, const float* __restrict__ slot_w,
                             float* __restrict__ out) {
    const int e = blockIdx.z, mt = blockIdx.y, nt = blockIdx.x;
    const int base = offs[e];
    const int cnt = offs[e + 1] - base;
    if (mt * 128 >= cnt) return;

    __shared__ __align__(16) short sA[128 * 32];
    __shared__ __align__(16) short sB[128 * 32];

    const int tid = threadIdx.x, wid = tid >> 6, lane = tid & 63;

    const short* srcA[2];
    const short* srcB[2];
#pragma unroll
    for (int j = 0; j < 2; ++j) {
        int c = j * 256 + tid;
        int row = c >> 2, c8 = c & 3;
        int slotc = min(base + mt * 128 + row, base + cnt - 1);
        srcA[j] = H + (size_t)slotc * F_DIM + c8 * 8;
        srcB[j] = w2b + ((size_t)e * D_DIM + nt * 128 + row) * F_DIM + c8 * 8;
    }

    const int wm = wid >> 1, wn = wid & 1;
    const int fr = lane & 15, fk = lane >> 4;

    f32x4 acc[4][4];
#pragma unroll
    for (int i = 0; i < 4; ++i)
#pragma unroll
        for (int j = 0; j < 4; ++j) acc[i][j] = (f32x4){0.f, 0.f, 0.f, 0.f};

    for (int k0 = 0; k0 < F_DIM; k0 += 32) {
#pragma unroll
        for (int j = 0; j < 2; ++j) {
            gload16(srcA[j] + k0, &sA[(j * 256 + wid * 64) * 8]);
            gload16(srcB[j] + k0, &sB[(j * 256 + wid * 64) * 8]);
        }
        __syncthreads();
        short8 af[4], bfr[4];
#pragma unroll
        for (int i = 0; i < 4; ++i) af[i] = *(const short8*)&sA[(wm * 64 + i * 16 + fr) * 32 + fk * 8];
#pragma unroll
        for (int i = 0; i < 4; ++i) bfr[i] = *(const short8*)&sB[(wn * 64 + i * 16 + fr) * 32 + fk * 8];
#pragma unroll
        for (int i = 0; i < 4; ++i)
#pragma unroll
            for (int j = 0; j < 4; ++j)
                acc[i][j] = __builtin_amdgcn_mfma_f32_16x16x32_bf16(af[i], bfr[j], acc[i][j], 0, 0, 0);
        __syncthreads();
    }

    // epilogue: bias, scale by gate weight, atomic accumulate into out[token]
#pragma unroll
    for (int i = 0; i < 4; ++i) {
        int mrow_base = mt * 128 + wm * 64 + i * 16 + (lane >> 4) * 4;
#pragma unroll
        for (int r = 0; r < 4; ++r) {
            int mrow = mrow_base + r;
            if (mrow < cnt) {
                int slot = base + mrow;
                int tok = token_list[slot];
                float w = slot_w[slot];
#pragma unroll
                for (int j = 0; j < 4; ++j) {
                    int ncol = nt * 128 + wn * 64 + j * 16 + (lane & 15);
                    float v = (acc[i][j][r] + b2[(size_t)e * D_DIM + ncol]) * w;
                    atomicAdd(&out[(size_t)tok * D_DIM + ncol], v);
                }
            }
        }
    }
}

// ---------------------------------------------------------------------------
extern "C" void kernel_launch(void* const* d_in, const int* in_sizes, int n_in,
                              void* d_out, int out_size, void* d_ws, size_t ws_size,
                              hipStream_t stream) {
    const float* x      = (const float*)d_in[0];
    const float* gate_w = (const float*)d_in[1];
    const float* w1     = (const float*)d_in[2];
    const float* b1     = (const float*)d_in[3];
    const float* w2     = (const float*)d_in[4];
    const float* b2     = (const float*)d_in[5];

    float* out   = (float*)d_out;                    // [T, D]
    float* probs = out + (size_t)T_TOK * D_DIM;      // [T, E]

    // workspace layout (needs ~286 MB)
    char* w = (char*)d_ws;
    int* counts = (int*)w;                 // 8 ints @ 0
    int* offs   = (int*)(w + 64);          // 9 ints @ 64
    size_t off = 256;
    int4*   idxrank    = (int4*)(w + off);  off += (size_t)T_TOK * 16;
    float2* ww_        = (float2*)(w + off); off += (size_t)T_TOK * 8;
    int*    token_list = (int*)(w + off);   off += (size_t)T_TOK * KTOP * 4;
    float*  slot_w     = (float*)(w + off); off += (size_t)T_TOK * KTOP * 4;
    short*  xb  = (short*)(w + off); off += (size_t)T_TOK * D_DIM * 2;
    short*  w1b = (short*)(w + off); off += (size_t)E_NUM * F_DIM * D_DIM * 2;
    short*  w2b = (short*)(w + off); off += (size_t)E_NUM * D_DIM * F_DIM * 2;
    short*  H   = (short*)(w + off); off += (size_t)T_TOK * KTOP * F_DIM * 2;
    (void)ws_size; // if ws_size < off we will fail validation -> revisit layout

    hipMemsetAsync(out, 0, (size_t)T_TOK * D_DIM * sizeof(float), stream);
    hipMemsetAsync(counts, 0, 64, stream);

    cvt_kernel<<<2048, 256, 0, stream>>>(x, xb, T_TOK * D_DIM / 8);
    cvt_kernel<<<4096, 256, 0, stream>>>(w1, w1b, E_NUM * F_DIM * D_DIM / 8);
    cvt_kernel<<<4096, 256, 0, stream>>>(w2, w2b, E_NUM * D_DIM * F_DIM / 8);

    gate_kernel<<<T_TOK / 4, 256, 0, stream>>>(x, gate_w, probs, idxrank, ww_, counts);
    scan_kernel<<<1, 64, 0, stream>>>(counts, offs);
    scatter_kernel<<<T_TOK / 256, 256, 0, stream>>>(idxrank, ww_, offs, token_list, slot_w);

    gemm1_kernel<<<dim3(F_DIM / 128, T_TOK / 128, E_NUM), 256, 0, stream>>>(
        xb, w1b, b1, offs, token_list, H);
    gemm2_kernel<<<dim3(D_DIM / 128, T_TOK / 128, E_NUM), 256, 0, stream>>>(
        H, w2b, b2, offs, token_list, slot_w, out);
}

// Round 2
// 1076.113 us; speedup vs baseline: 1.0058x; 1.0058x over previous
//
#include <hip/hip_runtime.h>
#include <hip/hip_bf16.h>

typedef __attribute__((ext_vector_type(8))) short short8;
typedef __attribute__((ext_vector_type(4))) float f32x4;
typedef unsigned int uint;

#define T_TOK 8192
#define D_DIM 1024
#define F_DIM 4096
#define E_NUM 8
#define KTOP 2

// ---------------------------------------------------------------------------
// Chunked bijective XCD swizzle: consecutive post-swizzle ids land on the
// SAME XCD (dispatch is round-robin over 8 XCDs). Requires nwg % 8 == 0.
// ---------------------------------------------------------------------------
__device__ __forceinline__ int xcd_swizzle(int bid, int nwg) {
    return (bid & 7) * (nwg >> 3) + (bid >> 3);
}

// ---------------------------------------------------------------------------
// fp32 -> bf16 convert (8 elems/thread/iter, vectorized)
// ---------------------------------------------------------------------------
__global__ void cvt_kernel(const float* __restrict__ in, short* __restrict__ out, int n8) {
    int i = blockIdx.x * blockDim.x + threadIdx.x;
    int stride = gridDim.x * blockDim.x;
    for (; i < n8; i += stride) {
        const float4* p = (const float4*)(in + (size_t)i * 8);
        float4 a = p[0], b = p[1];
        float va[8] = {a.x, a.y, a.z, a.w, b.x, b.y, b.z, b.w};
        short8 o;
#pragma unroll
        for (int j = 0; j < 8; ++j) {
            __hip_bfloat16 h = __float2bfloat16(va[j]);
            o[j] = *reinterpret_cast<short*>(&h);
        }
        *(short8*)(out + (size_t)i * 8) = o;
    }
}

// ---------------------------------------------------------------------------
// Gate: logits (fp32), softmax -> probs output, top-2, counts
// ---------------------------------------------------------------------------
__global__ void gate_kernel(const float* __restrict__ x, const float* __restrict__ gw,
                            float* __restrict__ probs, int4* __restrict__ idxrank,
                            float2* __restrict__ ww, int* __restrict__ counts) {
    const int lane = threadIdx.x & 63;
    const int wid = threadIdx.x >> 6;
    const int t = blockIdx.x * 4 + wid;
    const float4* xr = (const float4*)(x + (size_t)t * D_DIM);
    float acc[E_NUM];
#pragma unroll
    for (int e = 0; e < E_NUM; ++e) acc[e] = 0.f;
    for (int i = lane; i < D_DIM / 4; i += 64) {
        float4 xv = xr[i];
#pragma unroll
        for (int e = 0; e < E_NUM; ++e) {
            float4 gv = ((const float4*)(gw + (size_t)e * D_DIM))[i];
            acc[e] += xv.x * gv.x + xv.y * gv.y + xv.z * gv.z + xv.w * gv.w;
        }
    }
#pragma unroll
    for (int e = 0; e < E_NUM; ++e) {
#pragma unroll
        for (int off = 32; off > 0; off >>= 1) acc[e] += __shfl_xor(acc[e], off);
    }
    if (lane == 0) {
        float m = acc[0];
        for (int e = 1; e < E_NUM; ++e) m = fmaxf(m, acc[e]);
        float p[E_NUM], s = 0.f;
        for (int e = 0; e < E_NUM; ++e) { p[e] = expf(acc[e] - m); s += p[e]; }
        float inv = 1.f / s;
        for (int e = 0; e < E_NUM; ++e) {
            p[e] *= inv;
            probs[(size_t)t * E_NUM + e] = p[e];
        }
        float v0 = -1.f, v1 = -1.f; int i0 = 0, i1 = 0;
        for (int e = 0; e < E_NUM; ++e) {
            float v = p[e];
            if (v > v0) { v1 = v0; i1 = i0; v0 = v; i0 = e; }
            else if (v > v1) { v1 = v; i1 = e; }
        }
        float wsum = v0 + v1 + 1e-9f;
        int r0 = atomicAdd(&counts[i0], 1);
        int r1 = atomicAdd(&counts[i1], 1);
        idxrank[t] = make_int4(i0, i1, r0, r1);
        ww[t] = make_float2(v0 / wsum, v1 / wsum);
    }
}

__global__ void scan_kernel(const int* __restrict__ counts, int* __restrict__ offs) {
    if (threadIdx.x == 0 && blockIdx.x == 0) {
        int a = 0;
        for (int e = 0; e < E_NUM; ++e) { offs[e] = a; a += counts[e]; }
        offs[E_NUM] = a;
    }
}

__global__ void scatter_kernel(const int4* __restrict__ idxrank, const float2* __restrict__ ww,
                               const int* __restrict__ offs, int* __restrict__ token_list,
                               float* __restrict__ slot_w) {
    int t = blockIdx.x * blockDim.x + threadIdx.x;
    if (t >= T_TOK) return;
    int4 ir = idxrank[t];
    float2 w = ww[t];
    int s0 = offs[ir.x] + ir.z;
    int s1 = offs[ir.y] + ir.w;
    token_list[s0] = t; slot_w[s0] = w.x;
    token_list[s1] = t; slot_w[s1] = w.y;
}

// ---------------------------------------------------------------------------
// global -> LDS direct (16B per lane)
// ---------------------------------------------------------------------------
__device__ __forceinline__ void gload16(const void* g, void* l) {
    __builtin_amdgcn_global_load_lds((const __attribute__((address_space(1))) uint*)g,
                                     (__attribute__((address_space(3))) uint*)l, 16, 0, 0);
}

// ---------------------------------------------------------------------------
// Grouped GEMM1: H[slot, :] = gelu( x[token_list[slot], :] @ w1[e]^T + b1[e] )
// 128x128 tile, BK=32, 4 waves (2x2), 16x16x32 bf16 MFMA (m97 structure).
// 1D grid, XCD-swizzled, mt FASTEST (concurrent blocks share B-tile; x_e
// (~4MB gathered) stays L2-resident for the whole expert on its XCD).
// ---------------------------------------------------------------------------
#define G1_MT (T_TOK / 128)   // 64
#define G1_NT (F_DIM / 128)   // 32
__global__ void gemm1_kernel(const short* __restrict__ xb, const short* __restrict__ w1b,
                             const float* __restrict__ b1, const int* __restrict__ offs,
                             const int* __restrict__ token_list, short* __restrict__ H) {
    const int nwg = G1_MT * G1_NT * E_NUM;
    int sid = xcd_swizzle(blockIdx.x, nwg);
    const int mt = sid % G1_MT;
    const int nt = (sid / G1_MT) % G1_NT;
    const int e  = sid / (G1_MT * G1_NT);

    const int base = offs[e];
    const int cnt = offs[e + 1] - base;
    if (mt * 128 >= cnt) return;

    __shared__ __align__(16) short sA[128 * 32];
    __shared__ __align__(16) short sB[128 * 32];

    const int tid = threadIdx.x, wid = tid >> 6, lane = tid & 63;

    const short* srcA[2];
    const short* srcB[2];
#pragma unroll
    for (int j = 0; j < 2; ++j) {
        int c = j * 256 + tid;
        int row = c >> 2, c8 = c & 3;
        int slot = base + mt * 128 + row;
        int slotc = min(slot, base + cnt - 1);
        int tok = token_list[slotc];
        srcA[j] = xb + (size_t)tok * D_DIM + c8 * 8;
        srcB[j] = w1b + ((size_t)e * F_DIM + nt * 128 + row) * D_DIM + c8 * 8;
    }

    const int wm = wid >> 1, wn = wid & 1;
    const int fr = lane & 15, fk = lane >> 4;

    f32x4 acc[4][4];
#pragma unroll
    for (int i = 0; i < 4; ++i)
#pragma unroll
        for (int j = 0; j < 4; ++j) acc[i][j] = (f32x4){0.f, 0.f, 0.f, 0.f};

    for (int k0 = 0; k0 < D_DIM; k0 += 32) {
#pragma unroll
        for (int j = 0; j < 2; ++j) {
            gload16(srcA[j] + k0, &sA[(j * 256 + wid * 64) * 8]);
            gload16(srcB[j] + k0, &sB[(j * 256 + wid * 64) * 8]);
        }
        __syncthreads();
        short8 af[4], bfr[4];
#pragma unroll
        for (int i = 0; i < 4; ++i) af[i] = *(const short8*)&sA[(wm * 64 + i * 16 + fr) * 32 + fk * 8];
#pragma unroll
        for (int i = 0; i < 4; ++i) bfr[i] = *(const short8*)&sB[(wn * 64 + i * 16 + fr) * 32 + fk * 8];
#pragma unroll
        for (int i = 0; i < 4; ++i)
#pragma unroll
            for (int j = 0; j < 4; ++j)
                acc[i][j] = __builtin_amdgcn_mfma_f32_16x16x32_bf16(af[i], bfr[j], acc[i][j], 0, 0, 0);
        __syncthreads();
    }

#pragma unroll
    for (int i = 0; i < 4; ++i) {
        int mrow_base = mt * 128 + wm * 64 + i * 16 + (lane >> 4) * 4;
#pragma unroll
        for (int j = 0; j < 4; ++j) {
            int ncol = nt * 128 + wn * 64 + j * 16 + (lane & 15);
            float bias = b1[(size_t)e * F_DIM + ncol];
#pragma unroll
            for (int r = 0; r < 4; ++r) {
                int mrow = mrow_base + r;
                if (mrow < cnt) {
                    float v = acc[i][j][r] + bias;
                    v = 0.5f * v * (1.f + erff(v * 0.70710678118654752f));
                    __hip_bfloat16 h = __float2bfloat16(v);
                    H[(size_t)(base + mrow) * F_DIM + ncol] = *reinterpret_cast<short*>(&h);
                }
            }
        }
    }
}

// ---------------------------------------------------------------------------
// Grouped GEMM2: out[token, :] += slot_w * ( H[slot, :] @ w2[e]^T + b2[e] )
// 1D grid, XCD-swizzled, nt FASTEST (the 8 nt-blocks sharing an A-tile (H
// rows, 1MB) colocate on one XCD -> A fetched once; w2_e served by L3).
// ---------------------------------------------------------------------------
#define G2_MT (T_TOK / 128)   // 64
#define G2_NT (D_DIM / 128)   // 8
__global__ void gemm2_kernel(const short* __restrict__ H, const short* __restrict__ w2b,
                             const float* __restrict__ b2, const int* __restrict__ offs,
                             const int* __restrict__ token_list, const float* __restrict__ slot_w,
                             float* __restrict__ out) {
    const int nwg = G2_MT * G2_NT * E_NUM;
    int sid = xcd_swizzle(blockIdx.x, nwg);
    const int nt = sid % G2_NT;
    const int mt = (sid / G2_NT) % G2_MT;
    const int e  = sid / (G2_NT * G2_MT);

    const int base = offs[e];
    const int cnt = offs[e + 1] - base;
    if (mt * 128 >= cnt) return;

    __shared__ __align__(16) short sA[128 * 32];
    __shared__ __align__(16) short sB[128 * 32];

    const int tid = threadIdx.x, wid = tid >> 6, lane = tid & 63;

    const short* srcA[2];
    const short* srcB[2];
#pragma unroll
    for (int j = 0; j < 2; ++j) {
        int c = j * 256 + tid;
        int row = c >> 2, c8 = c & 3;
        int slotc = min(base + mt * 128 + row, base + cnt - 1);
        srcA[j] = H + (size_t)slotc * F_DIM + c8 * 8;
        srcB[j] = w2b + ((size_t)e * D_DIM + nt * 128 + row) * F_DIM + c8 * 8;
    }

    const int wm = wid >> 1, wn = wid & 1;
    const int fr = lane & 15, fk = lane >> 4;

    f32x4 acc[4][4];
#pragma unroll
    for (int i = 0; i < 4; ++i)
#pragma unroll
        for (int j = 0; j < 4; ++j) acc[i][j] = (f32x4){0.f, 0.f, 0.f, 0.f};

    for (int k0 = 0; k0 < F_DIM; k0 += 32) {
#pragma unroll
        for (int j = 0; j < 2; ++j) {
            gload16(srcA[j] + k0, &sA[(j * 256 + wid * 64) * 8]);
            gload16(srcB[j] + k0, &sB[(j * 256 + wid * 64) * 8]);
        }
        __syncthreads();
        short8 af[4], bfr[4];
#pragma unroll
        for (int i = 0; i < 4; ++i) af[i] = *(const short8*)&sA[(wm * 64 + i * 16 + fr) * 32 + fk * 8];
#pragma unroll
        for (int i = 0; i < 4; ++i) bfr[i] = *(const short8*)&sB[(wn * 64 + i * 16 + fr) * 32 + fk * 8];
#pragma unroll
        for (int i = 0; i < 4; ++i)
#pragma unroll
            for (int j = 0; j < 4; ++j)
                acc[i][j] = __builtin_amdgcn_mfma_f32_16x16x32_bf16(af[i], bfr[j], acc[i][j], 0, 0, 0);
        __syncthreads();
    }

#pragma unroll
    for (int i = 0; i < 4; ++i) {
        int mrow_base = mt * 128 + wm * 64 + i * 16 + (lane >> 4) * 4;
#pragma unroll
        for (int r = 0; r < 4; ++r) {
            int mrow = mrow_base + r;
            if (mrow < cnt) {
                int slot = base + mrow;
                int tok = token_list[slot];
                float w = slot_w[slot];
#pragma unroll
                for (int j = 0; j < 4; ++j) {
                    int ncol = nt * 128 + wn * 64 + j * 16 + (lane & 15);
                    float v = (acc[i][j][r] + b2[(size_t)e * D_DIM + ncol]) * w;
                    atomicAdd(&out[(size_t)tok * D_DIM + ncol], v);
                }
            }
        }
    }
}

// ---------------------------------------------------------------------------
extern "C" void kernel_launch(void* const* d_in, const int* in_sizes, int n_in,
                              void* d_out, int out_size, void* d_ws, size_t ws_size,
                              hipStream_t stream) {
    const float* x      = (const float*)d_in[0];
    const float* gate_w = (const float*)d_in[1];
    const float* w1     = (const float*)d_in[2];
    const float* b1     = (const float*)d_in[3];
    const float* w2     = (const float*)d_in[4];
    const float* b2     = (const float*)d_in[5];

    float* out   = (float*)d_out;                    // [T, D]
    float* probs = out + (size_t)T_TOK * D_DIM;      // [T, E]

    char* w = (char*)d_ws;
    int* counts = (int*)w;
    int* offs   = (int*)(w + 64);
    size_t off = 256;
    int4*   idxrank    = (int4*)(w + off);  off += (size_t)T_TOK * 16;
    float2* ww_        = (float2*)(w + off); off += (size_t)T_TOK * 8;
    int*    token_list = (int*)(w + off);   off += (size_t)T_TOK * KTOP * 4;
    float*  slot_w     = (float*)(w + off); off += (size_t)T_TOK * KTOP * 4;
    short*  xb  = (short*)(w + off); off += (size_t)T_TOK * D_DIM * 2;
    short*  w1b = (short*)(w + off); off += (size_t)E_NUM * F_DIM * D_DIM * 2;
    short*  w2b = (short*)(w + off); off += (size_t)E_NUM * D_DIM * F_DIM * 2;
    short*  H   = (short*)(w + off); off += (size_t)T_TOK * KTOP * F_DIM * 2;
    (void)ws_size;

    hipMemsetAsync(out, 0, (size_t)T_TOK * D_DIM * sizeof(float), stream);
    hipMemsetAsync(counts, 0, 64, stream);

    cvt_kernel<<<2048, 256, 0, stream>>>(x, xb, T_TOK * D_DIM / 8);
    cvt_kernel<<<4096, 256, 0, stream>>>(w1, w1b, E_NUM * F_DIM * D_DIM / 8);
    cvt_kernel<<<4096, 256, 0, stream>>>(w2, w2b, E_NUM * D_DIM * F_DIM / 8);

    gate_kernel<<<T_TOK / 4, 256, 0, stream>>>(x, gate_w, probs, idxrank, ww_, counts);
    scan_kernel<<<1, 64, 0, stream>>>(counts, offs);
    scatter_kernel<<<T_TOK / 256, 256, 0, stream>>>(idxrank, ww_, offs, token_list, slot_w);

    gemm1_kernel<<<G1_MT * G1_NT * E_NUM, 256, 0, stream>>>(
        xb, w1b, b1, offs, token_list, H);
    gemm2_kernel<<<G2_MT * G2_NT * E_NUM, 256, 0, stream>>>(
        H, w2b, b2, offs, token_list, slot_w, out);
}